// Round 2
// baseline (15661.197 us; speedup 1.0000x reference)
//
#include <hip/hip_runtime.h>
#include <math.h>

#define TT 256
#define BB 256
#define ID 512
#define HD 512
#define G4 2048            // 4*H
#define KT 1024            // IN + H
#define TBH ((size_t)TT * BB * HD)

typedef short bf16x8 __attribute__((ext_vector_type(8)));
typedef float f32x4  __attribute__((ext_vector_type(4)));
typedef unsigned short u16;
typedef u16  u16x8 __attribute__((ext_vector_type(8)));
typedef u16  u16x4 __attribute__((ext_vector_type(4)));

__device__ __forceinline__ u16 f2b(float f) {
    unsigned u = __builtin_bit_cast(unsigned, f);
    return (u16)((u + 0x7fffu + ((u >> 16) & 1u)) >> 16);   // RNE
}
__device__ __forceinline__ float b2f(u16 b) {
    unsigned u = ((unsigned)b) << 16;
    return __builtin_bit_cast(float, u);
}
__device__ __forceinline__ float sigm(float x) { return 1.f / (1.f + __expf(-x)); }
__device__ __forceinline__ float tanh_f(float x) { return 1.f - 2.f / (1.f + __expf(2.f * x)); }

// ---------------------------------------------------------------------------
// Prep: Wcb[j][k] bf16, k<512 -> W_ih[j][k], else W_hh[j][k-512].
//       bc[j] = b_ih[j] + b_hh[j] (f32).
// ---------------------------------------------------------------------------
__global__ void prep_kernel(const float* __restrict__ W_ih,
                            const float* __restrict__ W_hh,
                            const float* __restrict__ b_ih,
                            const float* __restrict__ b_hh,
                            u16* __restrict__ Wcb, float* __restrict__ bc) {
    int idx = blockIdx.x * 256 + threadIdx.x;   // over 2048*1024
    int j = idx >> 10;
    int k = idx & (KT - 1);
    float v = (k < ID) ? W_ih[(size_t)j * ID + k] : W_hh[(size_t)j * HD + (k - ID)];
    Wcb[idx] = f2b(v);
    if (idx < G4) bc[idx] = b_ih[idx] + b_hh[idx];
}

// ---------------------------------------------------------------------------
// Xproj GEMM: for each (t, bslice): Xp tiles = feat[t,bs*16..+16,:] @ W_ih^T + bc
// stored as bf16 in MFMA D-fragment layout:
//   Xp[(((t*16+bs)*128 + ct)*64 + lane)*4 + r],  ct = gatecol_base>>4
// Block: 1024 threads (16 waves), one (t,bs). Grid: 4096.
// ---------------------------------------------------------------------------
__launch_bounds__(1024)
__global__ void xproj_gemm(const float* __restrict__ feat,
                           const u16* __restrict__ Wcb,
                           const float* __restrict__ bc,
                           u16* __restrict__ Xp) {
    __shared__ u16 xA[16 * 520];    // [b][k] bf16, stride 520 (pad 8)
    const int tid = threadIdx.x;
    const int bx  = blockIdx.x;
    const int t   = bx >> 4;
    const int bs  = bx & 15;

    // stage x (16 rows x 512) -> bf16 LDS
    {
        int b = tid >> 6, j8 = (tid & 63) * 8;
        const float4* src = reinterpret_cast<const float4*>(
            feat + ((size_t)t * BB + bs * 16 + b) * ID + j8);
        float4 v0 = src[0], v1 = src[1];
        u16x8 p;
        p[0]=f2b(v0.x); p[1]=f2b(v0.y); p[2]=f2b(v0.z); p[3]=f2b(v0.w);
        p[4]=f2b(v1.x); p[5]=f2b(v1.y); p[6]=f2b(v1.z); p[7]=f2b(v1.w);
        *reinterpret_cast<u16x8*>(&xA[b * 520 + j8]) = p;
    }
    __syncthreads();

    const int w    = tid >> 6;
    const int lane = tid & 63;
    const int arow = lane & 15;
    const int kq   = (lane >> 4) * 8;

    f32x4 acc[8] = {};
    int colb[8];
    #pragma unroll
    for (int g = 0; g < 4; ++g)
        #pragma unroll
        for (int hh = 0; hh < 2; ++hh)
            colb[g * 2 + hh] = g * 512 + w * 32 + hh * 16;

    for (int kk = 0; kk < ID / 32; ++kk) {
        bf16x8 a = *reinterpret_cast<const bf16x8*>(&xA[arow * 520 + kk * 32 + kq]);
        #pragma unroll
        for (int tile = 0; tile < 8; ++tile) {
            const bf16x8 b = *reinterpret_cast<const bf16x8*>(
                Wcb + (size_t)(colb[tile] + (lane & 15)) * KT + kk * 32 + kq);
            acc[tile] = __builtin_amdgcn_mfma_f32_16x16x32_bf16(a, b, acc[tile], 0, 0, 0);
        }
    }

    #pragma unroll
    for (int tile = 0; tile < 8; ++tile) {
        float bias = bc[colb[tile] + (lane & 15)];
        int ct = colb[tile] >> 4;
        u16x4 p;
        #pragma unroll
        for (int r = 0; r < 4; ++r) p[r] = f2b(acc[tile][r] + bias);
        *reinterpret_cast<u16x4*>(Xp + (((size_t)bx * 128 + ct) * 64 + lane) * 4) = p;
    }
}

// ---------------------------------------------------------------------------
// Persistent LSTM: 16 blocks (one per 16-batch slice), 1024 threads (16 waves),
// loops t=0..255 internally. Wave w owns h-cols [32w,32w+32). c-state in regs.
// MODE 0: fused input projection (K=1024). MODE 1: Xproj precomputed (K=512).
// ---------------------------------------------------------------------------
template <int MODE>
__launch_bounds__(1024)
__global__ void lstm_persist(const float* __restrict__ feat,
                             const int*  __restrict__ mask,
                             const u16*  __restrict__ Wcb,
                             const float* __restrict__ bc,
                             const u16*  __restrict__ Xp,
                             float* __restrict__ out) {
    constexpr int KTOT = (MODE == 0) ? KT : HD;   // 1024 fused, 512 xproj
    constexpr int STR  = KTOT + 8;                // LDS row stride (bf16 elems)
    constexpr int HOFF = (MODE == 0) ? ID : 0;    // h offset within xh row

    __shared__ u16   xh[16 * STR];        // [b][k] bf16 operand rows
    __shared__ float hbuf[16 * 516];      // f32 h for coalesced out writes
    __shared__ float cbuf[16 * 516];

    const int tid  = threadIdx.x;
    const int bs   = blockIdx.x;
    const int w    = tid >> 6;
    const int lane = tid & 63;
    const int arow = lane & 15;           // A-fragment row (batch-in-slice)
    const int kq   = (lane >> 4) * 8;     // A/B fragment k sub-offset

    float* hxs0 = out;
    float* hxs1 = out + TBH;
    float* cxs  = out + 2 * TBH;

    // per-lane column constants
    int colh[2];                          // h-col for hh=0,1
    #pragma unroll
    for (int hh = 0; hh < 2; ++hh) colh[hh] = w * 32 + hh * 16 + (lane & 15);
    float bias[8];
    if (MODE == 0) {
        #pragma unroll
        for (int g = 0; g < 4; ++g)
            #pragma unroll
            for (int hh = 0; hh < 2; ++hh) bias[g * 2 + hh] = bc[g * 512 + colh[hh]];
    }
    // batches this lane owns in epilogue (D rows)
    int brow[4];
    #pragma unroll
    for (int r = 0; r < 4; ++r) brow[r] = (lane >> 4) * 4 + r;

    // zero xh (h part must start at 0)
    for (int i = tid; i < 16 * STR / 8; i += 1024)
        *reinterpret_cast<u16x8*>(&xh[i * 8]) = (u16x8)(u16)0;

    float c8[8] = {};                     // c-state: [hh*4+r]

    for (int t = 0; t < TT; ++t) {
        // ---- stage x_t (fused mode only) ----
        if (MODE == 0) {
            int b = tid >> 6, j8 = (tid & 63) * 8;
            const float4* src = reinterpret_cast<const float4*>(
                feat + ((size_t)t * BB + bs * 16 + b) * ID + j8);
            float4 v0 = src[0], v1 = src[1];
            u16x8 p;
            p[0]=f2b(v0.x); p[1]=f2b(v0.y); p[2]=f2b(v0.z); p[3]=f2b(v0.w);
            p[4]=f2b(v1.x); p[5]=f2b(v1.y); p[6]=f2b(v1.z); p[7]=f2b(v1.w);
            *reinterpret_cast<u16x8*>(&xh[b * STR + j8]) = p;
        }
        __syncthreads();                  // B1: xh ready (x staged, h from t-1)

        // ---- gate GEMM ----
        f32x4 acc[8];
        if (MODE == 1) {
            const u16* xp = Xp + (((size_t)(t * 16 + bs) * 128) * 64 + lane) * 4;
            #pragma unroll
            for (int g = 0; g < 4; ++g)
                #pragma unroll
                for (int hh = 0; hh < 2; ++hh) {
                    int ct = (g * 512 + w * 32 + hh * 16) >> 4;
                    u16x4 p = *reinterpret_cast<const u16x4*>(xp + (size_t)ct * 256);
                    f32x4 a; 
                    #pragma unroll
                    for (int r = 0; r < 4; ++r) a[r] = b2f(p[r]);
                    acc[g * 2 + hh] = a;
                }
        } else {
            #pragma unroll
            for (int i = 0; i < 8; ++i) acc[i] = (f32x4)0.f;
        }

        for (int kk = 0; kk < KTOT / 32; ++kk) {
            bf16x8 a = *reinterpret_cast<const bf16x8*>(&xh[arow * STR + kk * 32 + kq]);
            #pragma unroll
            for (int g = 0; g < 4; ++g)
                #pragma unroll
                for (int hh = 0; hh < 2; ++hh) {
                    int col = g * 512 + colh[hh];
                    // MODE 1 uses recurrent part of Wcb (k >= 512)
                    const bf16x8 b = *reinterpret_cast<const bf16x8*>(
                        Wcb + (size_t)col * KT + (KT - KTOT) + kk * 32 + kq);
                    acc[g * 2 + hh] =
                        __builtin_amdgcn_mfma_f32_16x16x32_bf16(a, b, acc[g * 2 + hh], 0, 0, 0);
                }
        }

        // ---- epilogue: pointwise cell update (all state lane-local) ----
        float kn[4], hn[8], cn[8];
        #pragma unroll
        for (int r = 0; r < 4; ++r) {
            int b = bs * 16 + brow[r];
            kn[r] = (t + 1 < TT) ? (1.f - (float)mask[(t + 1) * BB + b]) : 1.f;
        }
        #pragma unroll
        for (int hh = 0; hh < 2; ++hh)
            #pragma unroll
            for (int r = 0; r < 4; ++r) {
                float ig = acc[0 * 2 + hh][r];
                float fg = acc[1 * 2 + hh][r];
                float gg = acc[2 * 2 + hh][r];
                float og = acc[3 * 2 + hh][r];
                if (MODE == 0) {
                    ig += bias[0 * 2 + hh]; fg += bias[1 * 2 + hh];
                    gg += bias[2 * 2 + hh]; og += bias[3 * 2 + hh];
                }
                ig = sigm(ig); fg = sigm(fg); og = sigm(og); gg = tanh_f(gg);
                int i8 = hh * 4 + r;
                float c = fg * c8[i8] + ig * gg;     // c8 pre-scaled by keep
                cn[i8] = c;
                hn[i8] = og * tanh_f(c);
                c8[i8] = c * kn[r];
            }
        __syncthreads();                  // B2: everyone done reading xh

        // ---- write h (bf16, next-step-masked) + f32 outputs to LDS ----
        #pragma unroll
        for (int hh = 0; hh < 2; ++hh)
            #pragma unroll
            for (int r = 0; r < 4; ++r) {
                int i8 = hh * 4 + r;
                xh[brow[r] * STR + HOFF + colh[hh]] = f2b(hn[i8] * kn[r]);
                hbuf[brow[r] * 516 + colh[hh]] = hn[i8];
                cbuf[brow[r] * 516 + colh[hh]] = cn[i8];
            }
        __syncthreads();                  // B3: hbuf/cbuf complete

        // ---- coalesced global writes ----
        {
            int row = tid >> 6, off = (tid & 63) * 8;
            float4 h0 = *reinterpret_cast<const float4*>(&hbuf[row * 516 + off]);
            float4 h1 = *reinterpret_cast<const float4*>(&hbuf[row * 516 + off + 4]);
            float4 c0 = *reinterpret_cast<const float4*>(&cbuf[row * 516 + off]);
            float4 c1 = *reinterpret_cast<const float4*>(&cbuf[row * 516 + off + 4]);
            size_t o = ((size_t)t * BB + bs * 16 + row) * HD + off;
            *reinterpret_cast<float4*>(hxs0 + o)     = h0;
            *reinterpret_cast<float4*>(hxs0 + o + 4) = h1;
            *reinterpret_cast<float4*>(hxs1 + o)     = h0;
            *reinterpret_cast<float4*>(hxs1 + o + 4) = h1;
            *reinterpret_cast<float4*>(cxs + o)      = c0;
            *reinterpret_cast<float4*>(cxs + o + 4)  = c1;
        }
    }
}

extern "C" void kernel_launch(void* const* d_in, const int* in_sizes, int n_in,
                              void* d_out, int out_size, void* d_ws, size_t ws_size,
                              hipStream_t stream) {
    const float* feat = (const float*)d_in[0];
    const int*   mask = (const int*)d_in[1];
    const float* W_ih = (const float*)d_in[2];
    const float* W_hh = (const float*)d_in[3];
    const float* b_ih = (const float*)d_in[4];
    const float* b_hh = (const float*)d_in[5];
    float* out = (float*)d_out;

    u16*   Wcb = (u16*)d_ws;                                  // 4 MB
    float* bc  = (float*)(Wcb + (size_t)G4 * KT);             // 8 KB
    u16*   Xp  = (u16*)(bc + G4);                             // 256 MB

    const size_t needW = (size_t)G4 * KT * 2 + G4 * 4;
    const size_t needX = needW + (size_t)TT * BB * G4 * 2;

    prep_kernel<<<(G4 * KT) / 256, 256, 0, stream>>>(W_ih, W_hh, b_ih, b_hh, Wcb, bc);

    if (ws_size >= needX) {
        xproj_gemm<<<TT * 16, 1024, 0, stream>>>(feat, Wcb, bc, Xp);
        lstm_persist<1><<<16, 1024, 0, stream>>>(feat, mask, Wcb, bc, Xp, out);
    } else {
        lstm_persist<0><<<16, 1024, 0, stream>>>(feat, mask, Wcb, bc, Xp, out);
    }
}

// Round 3
// 5935.912 us; speedup vs baseline: 2.6384x; 2.6384x over previous
//
#include <hip/hip_runtime.h>
#include <math.h>

#define TT 256
#define BB 256
#define ID 512
#define HD 512
#define G4 2048            // 4*H
#define KT 1024            // IN + H
#define TBH ((size_t)TT * BB * HD)
#define NBLK 64            // cooperative step-kernel blocks (1 per CU, 64 <= 256 CUs)

typedef short bf16x8 __attribute__((ext_vector_type(8)));
typedef float f32x4  __attribute__((ext_vector_type(4)));
typedef unsigned short u16;
typedef u16  u16x8 __attribute__((ext_vector_type(8)));
typedef u16  u16x4 __attribute__((ext_vector_type(4)));

__device__ __forceinline__ u16 f2b(float f) {
    unsigned u = __builtin_bit_cast(unsigned, f);
    return (u16)((u + 0x7fffu + ((u >> 16) & 1u)) >> 16);   // RNE
}
__device__ __forceinline__ float b2f(u16 b) {
    unsigned u = ((unsigned)b) << 16;
    return __builtin_bit_cast(float, u);
}
__device__ __forceinline__ float sigm(float x) { return 1.f / (1.f + __expf(-x)); }
__device__ __forceinline__ float tanh_f(float x) { return 1.f - 2.f / (1.f + __expf(2.f * x)); }

// ===========================================================================
// FAST PATH (needs ~273 MB ws)
// ===========================================================================

// Prep: Wcb[col][k] bf16 (k<512: W_ih, else W_hh), bc = b_ih+b_hh,
// zero h double-buffer + barrier counter.
__global__ void prep_kernel(const float* __restrict__ W_ih,
                            const float* __restrict__ W_hh,
                            const float* __restrict__ b_ih,
                            const float* __restrict__ b_hh,
                            u16* __restrict__ Wcb, float* __restrict__ bc,
                            u16* __restrict__ hb, unsigned* __restrict__ bar) {
    int idx = blockIdx.x * 256 + threadIdx.x;   // 0 .. 2M-1
    int j = idx >> 10;
    int k = idx & (KT - 1);
    float v = (k < ID) ? W_ih[(size_t)j * ID + k] : W_hh[(size_t)j * HD + (k - ID)];
    Wcb[idx] = f2b(v);
    if (idx < G4) bc[idx] = b_ih[idx] + b_hh[idx];
    if (idx < 2 * BB * HD) hb[idx] = 0;
    if (idx == 0) *bar = 0u;
}

// Xproj: Xp = feat @ W_ih^T + (b_ih+b_hh), bf16, stored in MFMA D-fragment
// layout: Xp[((t*16 + mtile)*128 + ctile)*256 + lane*4 + r],
//   mtile = b>>4, ctile = gatecol>>4, (row=(lane>>4)*4+r, col=lane&15).
// Block: 64 rows (one t, 64 batches) x all 2048 cols. Grid 1024, 512 thr.
__launch_bounds__(512)
__global__ void xproj_gemm(const float* __restrict__ feat,
                           const u16* __restrict__ Wcb,
                           const float* __restrict__ bc,
                           u16* __restrict__ Xp) {
    __shared__ u16 xA[64 * 512];            // 64 KB, 16B-chunk XOR swizzled
    const int tid = threadIdx.x;
    const int blk = blockIdx.x;
    const int t   = blk >> 2;
    const int mb4 = blk & 3;                // batch block of 64

    for (int c = tid; c < 4096; c += 512) { // 64 rows x 64 chunks
        int row = c >> 6, k8 = c & 63;
        const float4* src = reinterpret_cast<const float4*>(
            feat + ((size_t)t * BB + mb4 * 64 + row) * ID + k8 * 8);
        float4 v0 = src[0], v1 = src[1];
        u16x8 p;
        p[0]=f2b(v0.x); p[1]=f2b(v0.y); p[2]=f2b(v0.z); p[3]=f2b(v0.w);
        p[4]=f2b(v1.x); p[5]=f2b(v1.y); p[6]=f2b(v1.z); p[7]=f2b(v1.w);
        *reinterpret_cast<u16x8*>(&xA[row * 512 + ((k8 ^ (row & 7)) * 8)]) = p;
    }
    __syncthreads();

    const int w = tid >> 6, lane = tid & 63;
    const int ms = w & 1;                   // row half (2 mtiles)
    const int wq = w >> 1;                  // col quarter (512 cols)
    const int r0 = ms * 32 + (lane & 15);
    const int r1 = r0 + 16;

    for (int grp = 0; grp < 4; ++grp) {     // 4 groups of 8 ctiles
        f32x4 acc[2][8] = {};
        for (int kk = 0; kk < 16; ++kk) {
            int c16 = kk * 4 + (lane >> 4);
            bf16x8 a0 = *reinterpret_cast<const bf16x8*>(&xA[r0 * 512 + ((c16 ^ (r0 & 7)) * 8)]);
            bf16x8 a1 = *reinterpret_cast<const bf16x8*>(&xA[r1 * 512 + ((c16 ^ (r1 & 7)) * 8)]);
            #pragma unroll
            for (int nt = 0; nt < 8; ++nt) {
                int col = wq * 512 + grp * 128 + nt * 16 + (lane & 15);
                bf16x8 b = *reinterpret_cast<const bf16x8*>(
                    Wcb + (size_t)col * KT + kk * 32 + (lane >> 4) * 8);
                acc[0][nt] = __builtin_amdgcn_mfma_f32_16x16x32_bf16(a0, b, acc[0][nt], 0, 0, 0);
                acc[1][nt] = __builtin_amdgcn_mfma_f32_16x16x32_bf16(a1, b, acc[1][nt], 0, 0, 0);
            }
        }
        #pragma unroll
        for (int mt = 0; mt < 2; ++mt) {
            int mtile = mb4 * 4 + ms * 2 + mt;
            #pragma unroll
            for (int nt = 0; nt < 8; ++nt) {
                int ct = wq * 32 + grp * 8 + nt;
                float bias = bc[ct * 16 + (lane & 15)];
                u16x4 pck;
                #pragma unroll
                for (int r = 0; r < 4; ++r) pck[r] = f2b(acc[mt][nt][r] + bias);
                *reinterpret_cast<u16x4*>(
                    Xp + (((size_t)t * 16 + mtile) * 128 + ct) * 256 + (size_t)lane * 4) = pck;
            }
        }
    }
}

// Cooperative step kernel: 64 blocks x 512 thr (8 waves). Block(mb,nb) owns
// batches [mb*64,+64) x hcols [nb*32,+32). W_hh cols LDS-stationary (128KB,
// swizzled). h double-buffered bf16 in ws. Device-wide barrier per step.
__launch_bounds__(512)
__global__ void lstm_coop(const int* __restrict__ mask,
                          const u16* __restrict__ Wcb,
                          const u16* __restrict__ Xp,
                          u16* __restrict__ hb,
                          unsigned* __restrict__ bar,
                          float* __restrict__ out) {
    __shared__ u16 Wl[128 * 512];           // 128 KB
    const int tid = threadIdx.x;
    const int mb = blockIdx.x & 3;
    const int nb = blockIdx.x >> 2;
    const int w = tid >> 6, lane = tid & 63;
    const int wr = w & 3;                   // batch 16-row subtile
    const int wc = w >> 2;                  // hcol 16-col subtile (0/1)

    // stage recurrent weights: local col cl = (g*2+wch)*16 + j
    for (int c = tid; c < 8192; c += 512) { // 128 cols x 64 chunks
        int cl = c >> 6, kc = c & 63;
        int ctl = cl >> 4, j = cl & 15;
        int g = ctl >> 1, wch = ctl & 1;
        int gcol = g * 512 + nb * 32 + wch * 16 + j;
        u16x8 v = *reinterpret_cast<const u16x8*>(Wcb + (size_t)gcol * KT + ID + kc * 8);
        *reinterpret_cast<u16x8*>(&Wl[cl * 512 + ((kc ^ (cl & 7)) * 8)]) = v;
    }
    __syncthreads();

    float* hxs0 = out;
    float* hxs1 = out + TBH;
    float* cxs  = out + 2 * TBH;

    const int jcol  = nb * 32 + wc * 16 + (lane & 15);   // this lane's hcol
    const int arow  = mb * 64 + wr * 16 + (lane & 15);   // A-fragment batch row
    const int mtile = mb * 4 + wr;
    int brow[4];
    #pragma unroll
    for (int r = 0; r < 4; ++r) brow[r] = mb * 64 + wr * 16 + (lane >> 4) * 4 + r;

    float c4[4] = {0.f, 0.f, 0.f, 0.f};
    int p = 0;

    for (int t = 0; t < TT; ++t) {
        // Xp fragments (HBM stream) — issue first, consumed after GEMM
        const u16* xpt = Xp + (((size_t)t * 16 + mtile) * 128) * 256 + (size_t)lane * 4;
        u16x4 xg[4];
        #pragma unroll
        for (int g = 0; g < 4; ++g)
            xg[g] = *reinterpret_cast<const u16x4*>(xpt + (size_t)(g * 32 + nb * 2 + wc) * 256);

        // A fragments from h buffer (L2/LLC)
        const u16* hbp = hb + (size_t)p * BB * HD;
        bf16x8 afr[16];
        #pragma unroll
        for (int kk = 0; kk < 16; ++kk)
            afr[kk] = *reinterpret_cast<const bf16x8*>(
                hbp + (size_t)arow * HD + kk * 32 + (lane >> 4) * 8);

        f32x4 acc[4] = {};
        #pragma unroll
        for (int kk = 0; kk < 16; ++kk) {
            int c16 = kk * 4 + (lane >> 4);
            #pragma unroll
            for (int g = 0; g < 4; ++g) {
                int cl = (g * 2 + wc) * 16 + (lane & 15);
                bf16x8 b = *reinterpret_cast<const bf16x8*>(&Wl[cl * 512 + ((c16 ^ (cl & 7)) * 8)]);
                acc[g] = __builtin_amdgcn_mfma_f32_16x16x32_bf16(afr[kk], b, acc[g], 0, 0, 0);
            }
        }

        // pointwise + writes
        u16* hbn = hb + (size_t)(p ^ 1) * BB * HD;
        #pragma unroll
        for (int r = 0; r < 4; ++r) {
            float kn = 1.f;
            if (t + 1 < TT) kn = 1.f - (float)mask[(t + 1) * BB + brow[r]];
            float ig = acc[0][r] + b2f(xg[0][r]);
            float fg = acc[1][r] + b2f(xg[1][r]);
            float gg = acc[2][r] + b2f(xg[2][r]);
            float og = acc[3][r] + b2f(xg[3][r]);
            ig = sigm(ig); fg = sigm(fg); og = sigm(og); gg = tanh_f(gg);
            float c = fg * c4[r] + ig * gg;
            float h = og * tanh_f(c);
            c4[r] = c * kn;
            hbn[(size_t)brow[r] * HD + jcol] = f2b(h * kn);
            size_t o = ((size_t)t * BB + brow[r]) * HD + jcol;
            hxs0[o] = h; hxs1[o] = h; cxs[o] = c;
        }

        // device-wide barrier (monotone counter, all 64 blocks resident)
        __threadfence();
        __syncthreads();
        if (tid == 0) {
            atomicAdd(bar, 1u);
            unsigned target = (unsigned)(t + 1) * NBLK;
            while (__hip_atomic_load(bar, __ATOMIC_ACQUIRE, __HIP_MEMORY_SCOPE_AGENT) < target)
                __builtin_amdgcn_s_sleep(2);
        }
        __syncthreads();
        p ^= 1;
    }
}

// ===========================================================================
// FALLBACK PATH (round-1, validated): per-step launches, fp32 VALU
// ===========================================================================
__global__ void prep_r1(const float* __restrict__ W_ih, const float* __restrict__ W_hh,
                        const float* __restrict__ b_ih, const float* __restrict__ b_hh,
                        float* __restrict__ WcT, float* __restrict__ bc) {
    int idx = blockIdx.x * 256 + threadIdx.x;
    int k = idx >> 11;
    int j = idx & (G4 - 1);
    float v = (k < ID) ? W_ih[(size_t)j * ID + k] : W_hh[(size_t)j * HD + (k - ID)];
    WcT[idx] = v;
    if (idx < G4) bc[idx] = b_ih[idx] + b_hh[idx];
}

__launch_bounds__(512, 2)
__global__ void lstm_step_r1(int t, int use_ws,
                             const float* __restrict__ feat, const int* __restrict__ mask,
                             const float* __restrict__ W_ih, const float* __restrict__ W_hh,
                             const float* __restrict__ b_ih, const float* __restrict__ b_hh,
                             const float* __restrict__ WcT, const float* __restrict__ bc,
                             float* __restrict__ out) {
    __shared__ float4 xh4[16][256];
    const int tid = threadIdx.x;
    const int c0 = blockIdx.x * 32;
    const int b0 = blockIdx.y * 16;
    float* hxs0 = out;
    float* hxs1 = out + TBH;
    float* cxs  = out + 2 * TBH;

    for (int e = tid; e < 16 * 256; e += 512) {
        int bl = e >> 8, q = e & 255, b = b0 + bl;
        float4 v;
        if (q < 128) {
            v = reinterpret_cast<const float4*>(feat + ((size_t)t * BB + b) * ID)[q];
        } else if (t == 0) {
            v = make_float4(0.f, 0.f, 0.f, 0.f);
        } else {
            float keep = 1.0f - (float)mask[t * BB + b];
            v = reinterpret_cast<const float4*>(hxs0 + ((size_t)(t - 1) * BB + b) * HD)[q - 128];
            v.x *= keep; v.y *= keep; v.z *= keep; v.w *= keep;
        }
        xh4[bl][q] = v;
    }
    __syncthreads();

    const int lc = tid & 127, bh = tid >> 7;
    const int j = (lc >> 5) * HD + c0 + (lc & 31);
    float acc[4] = {0.f, 0.f, 0.f, 0.f};
    if (use_ws) {
        for (int k = 0; k < KT; k += 4) {
            float w0 = WcT[(size_t)(k + 0) * G4 + j];
            float w1 = WcT[(size_t)(k + 1) * G4 + j];
            float w2 = WcT[(size_t)(k + 2) * G4 + j];
            float w3 = WcT[(size_t)(k + 3) * G4 + j];
            #pragma unroll
            for (int i = 0; i < 4; ++i) {
                float4 x = xh4[bh * 4 + i][k >> 2];
                acc[i] = fmaf(x.x, w0, acc[i]); acc[i] = fmaf(x.y, w1, acc[i]);
                acc[i] = fmaf(x.z, w2, acc[i]); acc[i] = fmaf(x.w, w3, acc[i]);
            }
        }
    } else {
        const float4* wi = reinterpret_cast<const float4*>(W_ih + (size_t)j * ID);
        const float4* wh = reinterpret_cast<const float4*>(W_hh + (size_t)j * HD);
        for (int k = 0; k < KT; k += 4) {
            float4 wv = (k < ID) ? wi[k >> 2] : wh[(k - ID) >> 2];
            #pragma unroll
            for (int i = 0; i < 4; ++i) {
                float4 x = xh4[bh * 4 + i][k >> 2];
                acc[i] = fmaf(x.x, wv.x, acc[i]); acc[i] = fmaf(x.y, wv.y, acc[i]);
                acc[i] = fmaf(x.z, wv.z, acc[i]); acc[i] = fmaf(x.w, wv.w, acc[i]);
            }
        }
    }
    float gbias = use_ws ? bc[j] : (b_ih[j] + b_hh[j]);
    __syncthreads();
    float* gbuf = reinterpret_cast<float*>(xh4);
    #pragma unroll
    for (int i = 0; i < 4; ++i) gbuf[lc * 16 + bh * 4 + i] = acc[i] + gbias;
    __syncthreads();
    {
        int hc = tid & 31, bl = tid >> 5, b = b0 + bl;
        float keep = 1.0f - (float)mask[t * BB + b];
        float cp = 0.f;
        if (t > 0) cp = cxs[((size_t)(t - 1) * BB + b) * HD + c0 + hc];
        cp *= keep;
        float ig = gbuf[(0 * 32 + hc) * 16 + bl];
        float fg = gbuf[(1 * 32 + hc) * 16 + bl];
        float gg = gbuf[(2 * 32 + hc) * 16 + bl];
        float og = gbuf[(3 * 32 + hc) * 16 + bl];
        ig = 1.0f / (1.0f + __expf(-ig));
        fg = 1.0f / (1.0f + __expf(-fg));
        gg = tanhf(gg);
        og = 1.0f / (1.0f + __expf(-og));
        float cn = fg * cp + ig * gg;
        float hn = og * tanhf(cn);
        size_t o = ((size_t)t * BB + b) * HD + c0 + hc;
        hxs0[o] = hn; hxs1[o] = hn; cxs[o] = cn;
    }
}

// ===========================================================================
extern "C" void kernel_launch(void* const* d_in, const int* in_sizes, int n_in,
                              void* d_out, int out_size, void* d_ws, size_t ws_size,
                              hipStream_t stream) {
    const float* feat = (const float*)d_in[0];
    const int*   mask = (const int*)d_in[1];
    const float* W_ih = (const float*)d_in[2];
    const float* W_hh = (const float*)d_in[3];
    const float* b_ih = (const float*)d_in[4];
    const float* b_hh = (const float*)d_in[5];
    float* out = (float*)d_out;

    // fast-path ws layout
    size_t offWcb = 0;
    size_t offBc  = offWcb + (size_t)G4 * KT * sizeof(u16);          // 4 MB
    size_t offHb  = offBc  + (size_t)G4 * sizeof(float);             // +8 KB
    size_t offBar = offHb  + (size_t)2 * BB * HD * sizeof(u16);      // +512 KB
    size_t offXp  = (offBar + 256 + 255) & ~(size_t)255;             // +256 B
    size_t need   = offXp + (size_t)TT * BB * G4 * sizeof(u16);      // +268.4 MB

    if (d_ws != nullptr && ws_size >= need) {
        char* ws = (char*)d_ws;
        u16*      Wcb = (u16*)(ws + offWcb);
        float*    bc  = (float*)(ws + offBc);
        u16*      hb  = (u16*)(ws + offHb);
        unsigned* bar = (unsigned*)(ws + offBar);
        u16*      Xp  = (u16*)(ws + offXp);

        prep_kernel<<<(G4 * KT) / 256, 256, 0, stream>>>(W_ih, W_hh, b_ih, b_hh, Wcb, bc, hb, bar);
        xproj_gemm<<<TT * (BB / 64), 512, 0, stream>>>(feat, Wcb, bc, Xp);
        lstm_coop<<<NBLK, 512, 0, stream>>>(mask, Wcb, Xp, hb, bar, out);
    } else {
        float* WcT = (float*)d_ws;
        float* bcf = WcT + (size_t)KT * G4;
        const size_t ws_needed = ((size_t)KT * G4 + G4) * sizeof(float);
        int use_ws = (d_ws != nullptr && ws_size >= ws_needed) ? 1 : 0;
        if (use_ws)
            prep_r1<<<(KT * G4) / 256, 256, 0, stream>>>(W_ih, W_hh, b_ih, b_hh, WcT, bcf);
        dim3 grid(16, 16);
        for (int t = 0; t < TT; ++t)
            lstm_step_r1<<<grid, 512, 0, stream>>>(t, use_ws, feat, mask,
                                                   W_ih, W_hh, b_ih, b_hh, WcT, bcf, out);
    }
}

// Round 4
// 3038.117 us; speedup vs baseline: 5.1549x; 1.9538x over previous
//
#include <hip/hip_runtime.h>
#include <math.h>

#define TT 256
#define BB 256
#define ID 512
#define HD 512
#define G4 2048            // 4*H
#define KT 1024            // IN + H
#define TBH ((size_t)TT * BB * HD)
#define NBLK 64            // cooperative step-kernel blocks (1 per CU)

typedef short bf16x8 __attribute__((ext_vector_type(8)));
typedef float f32x4  __attribute__((ext_vector_type(4)));
typedef unsigned short u16;
typedef u16  u16x8 __attribute__((ext_vector_type(8)));
typedef u16  u16x4 __attribute__((ext_vector_type(4)));

__device__ __forceinline__ u16 f2b(float f) {
    unsigned u = __builtin_bit_cast(unsigned, f);
    return (u16)((u + 0x7fffu + ((u >> 16) & 1u)) >> 16);   // RNE
}
__device__ __forceinline__ float b2f(u16 b) {
    unsigned u = ((unsigned)b) << 16;
    return __builtin_bit_cast(float, u);
}
__device__ __forceinline__ float sigm(float x) { return 1.f / (1.f + __expf(-x)); }
__device__ __forceinline__ float tanh_f(float x) { return 1.f - 2.f / (1.f + __expf(2.f * x)); }

// ===========================================================================
// FAST PATH (needs ~273 MB ws)
// ===========================================================================

__global__ void prep_kernel(const float* __restrict__ W_ih,
                            const float* __restrict__ W_hh,
                            const float* __restrict__ b_ih,
                            const float* __restrict__ b_hh,
                            u16* __restrict__ Wcb, float* __restrict__ bc,
                            u16* __restrict__ hb, unsigned* __restrict__ bar) {
    int idx = blockIdx.x * 256 + threadIdx.x;   // 0 .. 2M-1
    int j = idx >> 10;
    int k = idx & (KT - 1);
    float v = (k < ID) ? W_ih[(size_t)j * ID + k] : W_hh[(size_t)j * HD + (k - ID)];
    Wcb[idx] = f2b(v);
    if (idx < G4) bc[idx] = b_ih[idx] + b_hh[idx];
    if (idx < 2 * BB * HD) hb[idx] = 0;
    if (idx < 256) bar[idx] = 0u;
}

// Xproj: Xp = feat @ W_ih^T + (b_ih+b_hh), bf16, MFMA D-fragment layout:
// Xp[((t*16 + mtile)*128 + ctile)*256 + lane*4 + r]
__launch_bounds__(512)
__global__ void xproj_gemm(const float* __restrict__ feat,
                           const u16* __restrict__ Wcb,
                           const float* __restrict__ bc,
                           u16* __restrict__ Xp) {
    __shared__ u16 xA[64 * 512];            // 64 KB, 16B-chunk XOR swizzled
    const int tid = threadIdx.x;
    const int blk = blockIdx.x;
    const int t   = blk >> 2;
    const int mb4 = blk & 3;                // batch block of 64

    for (int c = tid; c < 4096; c += 512) { // 64 rows x 64 chunks
        int row = c >> 6, k8 = c & 63;
        const float4* src = reinterpret_cast<const float4*>(
            feat + ((size_t)t * BB + mb4 * 64 + row) * ID + k8 * 8);
        float4 v0 = src[0], v1 = src[1];
        u16x8 p;
        p[0]=f2b(v0.x); p[1]=f2b(v0.y); p[2]=f2b(v0.z); p[3]=f2b(v0.w);
        p[4]=f2b(v1.x); p[5]=f2b(v1.y); p[6]=f2b(v1.z); p[7]=f2b(v1.w);
        *reinterpret_cast<u16x8*>(&xA[row * 512 + ((k8 ^ (row & 7)) * 8)]) = p;
    }
    __syncthreads();

    const int w = tid >> 6, lane = tid & 63;
    const int ms = w & 1;
    const int wq = w >> 1;
    const int r0 = ms * 32 + (lane & 15);
    const int r1 = r0 + 16;

    for (int grp = 0; grp < 4; ++grp) {
        f32x4 acc[2][8] = {};
        for (int kk = 0; kk < 16; ++kk) {
            int c16 = kk * 4 + (lane >> 4);
            bf16x8 a0 = *reinterpret_cast<const bf16x8*>(&xA[r0 * 512 + ((c16 ^ (r0 & 7)) * 8)]);
            bf16x8 a1 = *reinterpret_cast<const bf16x8*>(&xA[r1 * 512 + ((c16 ^ (r1 & 7)) * 8)]);
            #pragma unroll
            for (int nt = 0; nt < 8; ++nt) {
                int col = wq * 512 + grp * 128 + nt * 16 + (lane & 15);
                bf16x8 b = *reinterpret_cast<const bf16x8*>(
                    Wcb + (size_t)col * KT + kk * 32 + (lane >> 4) * 8);
                acc[0][nt] = __builtin_amdgcn_mfma_f32_16x16x32_bf16(a0, b, acc[0][nt], 0, 0, 0);
                acc[1][nt] = __builtin_amdgcn_mfma_f32_16x16x32_bf16(a1, b, acc[1][nt], 0, 0, 0);
            }
        }
        #pragma unroll
        for (int mt = 0; mt < 2; ++mt) {
            int mtile = mb4 * 4 + ms * 2 + mt;
            #pragma unroll
            for (int nt = 0; nt < 8; ++nt) {
                int ct = wq * 32 + grp * 8 + nt;
                float bias = bc[ct * 16 + (lane & 15)];
                u16x4 pck;
                #pragma unroll
                for (int r = 0; r < 4; ++r) pck[r] = f2b(acc[mt][nt][r] + bias);
                *reinterpret_cast<u16x4*>(
                    Xp + (((size_t)t * 16 + mtile) * 128 + ct) * 256 + (size_t)lane * 4) = pck;
            }
        }
    }
}

// Cooperative step kernel: 64 blocks x 512 thr. Block(mb,nb): batches
// [mb*64,+64) x hcols [nb*32,+32). Weights LDS-stationary. h double-buffered
// bf16 in ws, published via write-through atomics. Barrier PER MB-GROUP (16
// blocks), relaxed poll + single acquire.
__launch_bounds__(512)
__global__ void lstm_coop(const int* __restrict__ mask,
                          const u16* __restrict__ Wcb,
                          const u16* __restrict__ Xp,
                          u16* __restrict__ hb,
                          unsigned* __restrict__ bar,
                          float* __restrict__ out) {
    __shared__ u16 Wl[128 * 512];           // 128 KB
    const int tid = threadIdx.x;
    const int mb = blockIdx.x & 3;
    const int nb = blockIdx.x >> 2;
    const int w = tid >> 6, lane = tid & 63;
    const int wr = w & 3;                   // batch 16-row subtile
    const int wc = w >> 2;                  // hcol 16-col subtile (0/1)

    for (int c = tid; c < 8192; c += 512) { // stage recurrent weights
        int cl = c >> 6, kc = c & 63;
        int ctl = cl >> 4, j = cl & 15;
        int g = ctl >> 1, wch = ctl & 1;
        int gcol = g * 512 + nb * 32 + wch * 16 + j;
        u16x8 v = *reinterpret_cast<const u16x8*>(Wcb + (size_t)gcol * KT + ID + kc * 8);
        *reinterpret_cast<u16x8*>(&Wl[cl * 512 + ((kc ^ (cl & 7)) * 8)]) = v;
    }
    __syncthreads();

    float* hxs0 = out;
    float* hxs1 = out + TBH;
    float* cxs  = out + 2 * TBH;

    const int jcol  = nb * 32 + wc * 16 + (lane & 15);
    const int arow  = mb * 64 + wr * 16 + (lane & 15);
    const int mtile = mb * 4 + wr;
    int brow[4];
    #pragma unroll
    for (int r = 0; r < 4; ++r) brow[r] = mb * 64 + wr * 16 + (lane >> 4) * 4 + r;

    unsigned* bar_g = bar + mb * 64;        // one counter per mb-group (256B apart)

    float c4[4] = {0.f, 0.f, 0.f, 0.f};
    int p = 0;

    // prologue: prefetch Xp(t=0) + keep(t=0)
    u16x4 xg[4];
    float kn[4];
    {
        const u16* xpt = Xp + (((size_t)0 * 16 + mtile) * 128) * 256 + (size_t)lane * 4;
        #pragma unroll
        for (int g = 0; g < 4; ++g)
            xg[g] = __builtin_nontemporal_load(
                reinterpret_cast<const u16x4*>(xpt + (size_t)(g * 32 + nb * 2 + wc) * 256));
        #pragma unroll
        for (int r = 0; r < 4; ++r)
            kn[r] = 1.f - (float)mask[1 * BB + brow[r]];
    }

    for (int t = 0; t < TT; ++t) {
        // A fragments (fresh after last step's acquire-inv)
        const u16* hbp = hb + (size_t)p * BB * HD;
        bf16x8 afr[16];
        #pragma unroll
        for (int kk = 0; kk < 16; ++kk)
            afr[kk] = *reinterpret_cast<const bf16x8*>(
                hbp + (size_t)arow * HD + kk * 32 + (lane >> 4) * 8);

        // prefetch next step's h-independent inputs (overlap with GEMM)
        u16x4 nxg[4];
        float nkn[4];
        if (t + 1 < TT) {
            const u16* xpt = Xp + (((size_t)(t + 1) * 16 + mtile) * 128) * 256 + (size_t)lane * 4;
            #pragma unroll
            for (int g = 0; g < 4; ++g)
                nxg[g] = __builtin_nontemporal_load(
                    reinterpret_cast<const u16x4*>(xpt + (size_t)(g * 32 + nb * 2 + wc) * 256));
        } else {
            #pragma unroll
            for (int g = 0; g < 4; ++g) nxg[g] = (u16x4)(u16)0;
        }
        #pragma unroll
        for (int r = 0; r < 4; ++r)
            nkn[r] = (t + 2 < TT) ? (1.f - (float)mask[(t + 2) * BB + brow[r]]) : 1.f;

        // gate GEMM
        f32x4 acc[4] = {};
        #pragma unroll
        for (int kk = 0; kk < 16; ++kk) {
            int c16 = kk * 4 + (lane >> 4);
            #pragma unroll
            for (int g = 0; g < 4; ++g) {
                int cl = (g * 2 + wc) * 16 + (lane & 15);
                bf16x8 b = *reinterpret_cast<const bf16x8*>(&Wl[cl * 512 + ((c16 ^ (cl & 7)) * 8)]);
                acc[g] = __builtin_amdgcn_mfma_f32_16x16x32_bf16(afr[kk], b, acc[g], 0, 0, 0);
            }
        }

        // pointwise + publish
        u16* hbn = hb + (size_t)(p ^ 1) * BB * HD;
        #pragma unroll
        for (int r = 0; r < 4; ++r) {
            float ig = acc[0][r] + b2f(xg[0][r]);
            float fg = acc[1][r] + b2f(xg[1][r]);
            float gg = acc[2][r] + b2f(xg[2][r]);
            float og = acc[3][r] + b2f(xg[3][r]);
            ig = sigm(ig); fg = sigm(fg); og = sigm(og); gg = tanh_f(gg);
            float c = fg * c4[r] + ig * gg;     // c4 pre-scaled by keep
            float h = og * tanh_f(c);
            c4[r] = c * kn[r];

            // publish next-h (bf16, masked) as packed u32 write-through atomics
            unsigned mine = (unsigned)f2b(h * kn[r]);
            unsigned oth  = (unsigned)__shfl_xor((int)mine, 1, 64);
            if (!(lane & 1)) {
                unsigned pk = (mine & 0xffffu) | (oth << 16);
                __hip_atomic_store(
                    reinterpret_cast<unsigned*>(hbn + (size_t)brow[r] * HD + jcol),
                    pk, __ATOMIC_RELAXED, __HIP_MEMORY_SCOPE_AGENT);
            }

            // streaming outputs (non-temporal: keep L2 clean)
            size_t o = ((size_t)t * BB + brow[r]) * HD + jcol;
            __builtin_nontemporal_store(h, hxs0 + o);
            __builtin_nontemporal_store(h, hxs1 + o);
            __builtin_nontemporal_store(c, cxs + o);
        }

        // --- mb-group barrier: release add, relaxed poll, single acquire ---
        asm volatile("s_waitcnt vmcnt(0)" ::: "memory");
        __syncthreads();
        if (tid == 0) {
            __hip_atomic_fetch_add(bar_g, 1u, __ATOMIC_RELEASE, __HIP_MEMORY_SCOPE_AGENT);
            unsigned target = (unsigned)(t + 1) * 16u;
            while (__hip_atomic_load(bar_g, __ATOMIC_RELAXED, __HIP_MEMORY_SCOPE_AGENT) < target)
                __builtin_amdgcn_s_sleep(1);
            (void)__hip_atomic_load(bar_g, __ATOMIC_ACQUIRE, __HIP_MEMORY_SCOPE_AGENT);
        }
        __syncthreads();

        #pragma unroll
        for (int g = 0; g < 4; ++g) xg[g] = nxg[g];
        #pragma unroll
        for (int r = 0; r < 4; ++r) kn[r] = nkn[r];
        p ^= 1;
    }
}

// ===========================================================================
// FALLBACK PATH (round-1, validated): per-step launches, fp32 VALU
// ===========================================================================
__global__ void prep_r1(const float* __restrict__ W_ih, const float* __restrict__ W_hh,
                        const float* __restrict__ b_ih, const float* __restrict__ b_hh,
                        float* __restrict__ WcT, float* __restrict__ bc) {
    int idx = blockIdx.x * 256 + threadIdx.x;
    int k = idx >> 11;
    int j = idx & (G4 - 1);
    float v = (k < ID) ? W_ih[(size_t)j * ID + k] : W_hh[(size_t)j * HD + (k - ID)];
    WcT[idx] = v;
    if (idx < G4) bc[idx] = b_ih[idx] + b_hh[idx];
}

__launch_bounds__(512, 2)
__global__ void lstm_step_r1(int t, int use_ws,
                             const float* __restrict__ feat, const int* __restrict__ mask,
                             const float* __restrict__ W_ih, const float* __restrict__ W_hh,
                             const float* __restrict__ b_ih, const float* __restrict__ b_hh,
                             const float* __restrict__ WcT, const float* __restrict__ bc,
                             float* __restrict__ out) {
    __shared__ float4 xh4[16][256];
    const int tid = threadIdx.x;
    const int c0 = blockIdx.x * 32;
    const int b0 = blockIdx.y * 16;
    float* hxs0 = out;
    float* hxs1 = out + TBH;
    float* cxs  = out + 2 * TBH;

    for (int e = tid; e < 16 * 256; e += 512) {
        int bl = e >> 8, q = e & 255, b = b0 + bl;
        float4 v;
        if (q < 128) {
            v = reinterpret_cast<const float4*>(feat + ((size_t)t * BB + b) * ID)[q];
        } else if (t == 0) {
            v = make_float4(0.f, 0.f, 0.f, 0.f);
        } else {
            float keep = 1.0f - (float)mask[t * BB + b];
            v = reinterpret_cast<const float4*>(hxs0 + ((size_t)(t - 1) * BB + b) * HD)[q - 128];
            v.x *= keep; v.y *= keep; v.z *= keep; v.w *= keep;
        }
        xh4[bl][q] = v;
    }
    __syncthreads();

    const int lc = tid & 127, bh = tid >> 7;
    const int j = (lc >> 5) * HD + c0 + (lc & 31);
    float acc[4] = {0.f, 0.f, 0.f, 0.f};
    if (use_ws) {
        for (int k = 0; k < KT; k += 4) {
            float w0 = WcT[(size_t)(k + 0) * G4 + j];
            float w1 = WcT[(size_t)(k + 1) * G4 + j];
            float w2 = WcT[(size_t)(k + 2) * G4 + j];
            float w3 = WcT[(size_t)(k + 3) * G4 + j];
            #pragma unroll
            for (int i = 0; i < 4; ++i) {
                float4 x = xh4[bh * 4 + i][k >> 2];
                acc[i] = fmaf(x.x, w0, acc[i]); acc[i] = fmaf(x.y, w1, acc[i]);
                acc[i] = fmaf(x.z, w2, acc[i]); acc[i] = fmaf(x.w, w3, acc[i]);
            }
        }
    } else {
        const float4* wi = reinterpret_cast<const float4*>(W_ih + (size_t)j * ID);
        const float4* wh = reinterpret_cast<const float4*>(W_hh + (size_t)j * HD);
        for (int k = 0; k < KT; k += 4) {
            float4 wv = (k < ID) ? wi[k >> 2] : wh[(k - ID) >> 2];
            #pragma unroll
            for (int i = 0; i < 4; ++i) {
                float4 x = xh4[bh * 4 + i][k >> 2];
                acc[i] = fmaf(x.x, wv.x, acc[i]); acc[i] = fmaf(x.y, wv.y, acc[i]);
                acc[i] = fmaf(x.z, wv.z, acc[i]); acc[i] = fmaf(x.w, wv.w, acc[i]);
            }
        }
    }
    float gbias = use_ws ? bc[j] : (b_ih[j] + b_hh[j]);
    __syncthreads();
    float* gbuf = reinterpret_cast<float*>(xh4);
    #pragma unroll
    for (int i = 0; i < 4; ++i) gbuf[lc * 16 + bh * 4 + i] = acc[i] + gbias;
    __syncthreads();
    {
        int hc = tid & 31, bl = tid >> 5, b = b0 + bl;
        float keep = 1.0f - (float)mask[t * BB + b];
        float cp = 0.f;
        if (t > 0) cp = cxs[((size_t)(t - 1) * BB + b) * HD + c0 + hc];
        cp *= keep;
        float ig = gbuf[(0 * 32 + hc) * 16 + bl];
        float fg = gbuf[(1 * 32 + hc) * 16 + bl];
        float gg = gbuf[(2 * 32 + hc) * 16 + bl];
        float og = gbuf[(3 * 32 + hc) * 16 + bl];
        ig = 1.0f / (1.0f + __expf(-ig));
        fg = 1.0f / (1.0f + __expf(-fg));
        gg = tanhf(gg);
        og = 1.0f / (1.0f + __expf(-og));
        float cn = fg * cp + ig * gg;
        float hn = og * tanhf(cn);
        size_t o = ((size_t)t * BB + b) * HD + c0 + hc;
        hxs0[o] = hn; hxs1[o] = hn; cxs[o] = cn;
    }
}

// ===========================================================================
extern "C" void kernel_launch(void* const* d_in, const int* in_sizes, int n_in,
                              void* d_out, int out_size, void* d_ws, size_t ws_size,
                              hipStream_t stream) {
    const float* feat = (const float*)d_in[0];
    const int*   mask = (const int*)d_in[1];
    const float* W_ih = (const float*)d_in[2];
    const float* W_hh = (const float*)d_in[3];
    const float* b_ih = (const float*)d_in[4];
    const float* b_hh = (const float*)d_in[5];
    float* out = (float*)d_out;

    size_t offWcb = 0;
    size_t offBc  = offWcb + (size_t)G4 * KT * sizeof(u16);          // 4 MB
    size_t offHb  = offBc  + (size_t)G4 * sizeof(float);             // +8 KB
    size_t offBar = offHb  + (size_t)2 * BB * HD * sizeof(u16);      // +512 KB
    size_t offXp  = (offBar + 1024 + 255) & ~(size_t)255;            // +1 KB
    size_t need   = offXp + (size_t)TT * BB * G4 * sizeof(u16);      // +268.4 MB

    if (d_ws != nullptr && ws_size >= need) {
        char* ws = (char*)d_ws;
        u16*      Wcb = (u16*)(ws + offWcb);
        float*    bc  = (float*)(ws + offBc);
        u16*      hb  = (u16*)(ws + offHb);
        unsigned* bar = (unsigned*)(ws + offBar);
        u16*      Xp  = (u16*)(ws + offXp);

        prep_kernel<<<(G4 * KT) / 256, 256, 0, stream>>>(W_ih, W_hh, b_ih, b_hh, Wcb, bc, hb, bar);
        xproj_gemm<<<TT * (BB / 64), 512, 0, stream>>>(feat, Wcb, bc, Xp);
        lstm_coop<<<NBLK, 512, 0, stream>>>(mask, Wcb, Xp, hb, bar, out);
    } else {
        float* WcT = (float*)d_ws;
        float* bcf = WcT + (size_t)KT * G4;
        const size_t ws_needed = ((size_t)KT * G4 + G4) * sizeof(float);
        int use_ws = (d_ws != nullptr && ws_size >= ws_needed) ? 1 : 0;
        if (use_ws)
            prep_r1<<<(KT * G4) / 256, 256, 0, stream>>>(W_ih, W_hh, b_ih, b_hh, WcT, bcf);
        dim3 grid(16, 16);
        for (int t = 0; t < TT; ++t)
            lstm_step_r1<<<grid, 512, 0, stream>>>(t, use_ws, feat, mask,
                                                   W_ih, W_hh, b_ih, b_hh, WcT, bcf, out);
    }
}